// Round 1
// baseline (5161.175 us; speedup 1.0000x reference)
//
#include <hip/hip_runtime.h>

#define NB 16
#define NL 64

__device__ __forceinline__ float sigf(float x){ return 1.0f/(1.0f + expf(-x)); }

// ---------------- k_prep: transpose w_hh (4096x1024) -> whhT[k][r] (1024x4096); zero levcnt
__global__ __launch_bounds__(256) void k_prep(const float* __restrict__ w_hh,
                                              float* __restrict__ whhT,
                                              int* __restrict__ levcnt){
  __shared__ float tl[32][33];
  int tr = blockIdx.x & 127;   // r tile [0,128)
  int tk = blockIdx.x >> 7;    // k tile [0,32)
  for (int idx = threadIdx.x; idx < 1024; idx += 256){
    int lr = idx >> 5, lk = idx & 31;
    tl[lr][lk] = w_hh[(tr*32 + lr)*1024 + tk*32 + lk];
  }
  __syncthreads();
  for (int idx = threadIdx.x; idx < 1024; idx += 256){
    int lk = idx >> 5, lr = idx & 31;
    whhT[(tk*32 + lk)*4096 + tr*32 + lr] = tl[lr][lk];
  }
  if (blockIdx.x == 0 && threadIdx.x < 64) levcnt[threadIdx.x] = 0;
}

// ---------------- k_rank: sc[bl] = relu(emb[bl]·w1[j]) · w2[j] summed over j
__global__ __launch_bounds__(128) void k_rank(const float* __restrict__ emb,
                                              const float* __restrict__ w1,
                                              const float* __restrict__ w2,
                                              float* __restrict__ SC){
  int bl = blockIdx.x;
  int j  = threadIdx.x;
  const float* e = emb + bl*1024;
  const float* w = w1 + j*1024;
  float acc = 0.f;
  for (int k = 0; k < 1024; k += 4){
    float4 ev = *(const float4*)(e + k);
    float4 wv = *(const float4*)(w + k);
    acc += ev.x*wv.x + ev.y*wv.y + ev.z*wv.z + ev.w*wv.w;
  }
  float s = fmaxf(acc, 0.f) * w2[j];
  __shared__ float red[128];
  red[j] = s;
  __syncthreads();
  for (int st = 64; st > 0; st >>= 1){
    if (j < st) red[j] += red[j + st];
    __syncthreads();
  }
  if (j == 0) SC[bl] = red[0];
}

// ---------------- k_gx: GX[bl][r] = emb[bl]·w_ih[r] + b_ih[r] + b_hh[r]   (M=1024,N=4096,K=1024)
__global__ __launch_bounds__(256) void k_gx(const float* __restrict__ emb,
                                            const float* __restrict__ w_ih,
                                            const float* __restrict__ b_ih,
                                            const float* __restrict__ b_hh,
                                            float* __restrict__ GX){
  __shared__ float As[64][17];
  __shared__ float Bs[16][68];
  int mt = blockIdx.x & 15;
  int nt = blockIdx.x >> 4;
  int m0 = mt*64, n0 = nt*64;
  int tm = threadIdx.x >> 4, tn = threadIdx.x & 15;
  float acc[4][4] = {};
  for (int k0 = 0; k0 < 1024; k0 += 16){
    {
      int r = threadIdx.x >> 2, c4 = (threadIdx.x & 3)*4;
      float4 v = *(const float4*)(emb + (m0 + r)*1024 + k0 + c4);
      As[r][c4+0]=v.x; As[r][c4+1]=v.y; As[r][c4+2]=v.z; As[r][c4+3]=v.w;
      float4 u = *(const float4*)(w_ih + (n0 + r)*1024 + k0 + c4);
      Bs[c4+0][r]=u.x; Bs[c4+1][r]=u.y; Bs[c4+2][r]=u.z; Bs[c4+3][r]=u.w;
    }
    __syncthreads();
    #pragma unroll
    for (int kk = 0; kk < 16; kk++){
      float a0 = As[tm*4+0][kk], a1 = As[tm*4+1][kk], a2 = As[tm*4+2][kk], a3 = As[tm*4+3][kk];
      float4 b4 = *(const float4*)&Bs[kk][tn*4];
      acc[0][0]+=a0*b4.x; acc[0][1]+=a0*b4.y; acc[0][2]+=a0*b4.z; acc[0][3]+=a0*b4.w;
      acc[1][0]+=a1*b4.x; acc[1][1]+=a1*b4.y; acc[1][2]+=a1*b4.z; acc[1][3]+=a1*b4.w;
      acc[2][0]+=a2*b4.x; acc[2][1]+=a2*b4.y; acc[2][2]+=a2*b4.z; acc[2][3]+=a2*b4.w;
      acc[3][0]+=a3*b4.x; acc[3][1]+=a3*b4.y; acc[3][2]+=a3*b4.z; acc[3][3]+=a3*b4.w;
    }
    __syncthreads();
  }
  float4 bi = *(const float4*)(b_ih + n0 + tn*4);
  float4 bh = *(const float4*)(b_hh + n0 + tn*4);
  #pragma unroll
  for (int ii = 0; ii < 4; ii++){
    int m = m0 + tm*4 + ii;
    float4 o;
    o.x = acc[ii][0] + bi.x + bh.x;
    o.y = acc[ii][1] + bi.y + bh.y;
    o.z = acc[ii][2] + bi.z + bh.z;
    o.w = acc[ii][3] + bi.w + bh.w;
    *(float4*)(GX + m*4096 + n0 + tn*4) = o;
  }
}

// ---------------- k_build: per-sentence greedy tree, levels, level lists, lps
__global__ __launch_bounds__(64) void k_build(const float* __restrict__ SC,
                                              const int* __restrict__ length,
                                              int* __restrict__ LCH, int* __restrict__ RCH,
                                              int* __restrict__ LEVCNT, int* __restrict__ LEVLIST,
                                              int* __restrict__ ROOTP,
                                              float* __restrict__ OUT){
  __shared__ float scl[64];
  __shared__ int stk_s[64], stk_e[64], order_l[64];
  __shared__ int isn_l[64], lev_l[64], ns_l[64], ne_l[64];
  int b = blockIdx.x;
  if (threadIdx.x < 64){
    scl[threadIdx.x] = SC[b*64 + threadIdx.x];
    isn_l[threadIdx.x] = 0;
  }
  __syncthreads();
  if (threadIdx.x == 0){
    int len = length[b];
    int cnt = 0, sp = 0;
    if (len >= 2){ stk_s[0] = 0; stk_e[0] = len; sp = 1; }
    while (sp > 0){
      sp--;
      int s = stk_s[sp], e = stk_e[sp];   // e-s >= 2 guaranteed
      int pos = s; float mx = scl[s];
      for (int q = s+1; q < e; q++){ if (scl[q] > mx){ mx = scl[q]; pos = q; } }
      order_l[cnt++] = pos;
      // left rep
      int lq;
      if (pos - s <= 0) lq = -1;
      else if (pos - s == 1) lq = s;
      else { lq = s; float m2 = scl[s]; for (int q = s+1; q < pos; q++){ if (scl[q] > m2){ m2 = scl[q]; lq = q; } } }
      // right rep
      int rq;
      if (e - (pos+1) <= 0) rq = -1;
      else if (e - (pos+1) == 1) rq = pos+1;
      else { rq = pos+1; float m2 = scl[pos+1]; for (int q = pos+2; q < e; q++){ if (scl[q] > m2){ m2 = scl[q]; rq = q; } } }
      LCH[b*64 + pos] = lq; RCH[b*64 + pos] = rq;
      ns_l[pos] = s; ne_l[pos] = e; isn_l[pos] = 1;
      if (pos - s >= 2){ stk_s[sp] = s; stk_e[sp] = pos; sp++; }
      if (e - pos - 1 >= 2){ stk_s[sp] = pos+1; stk_e[sp] = e; sp++; }
    }
    // levels (children recorded after parent -> reverse order is bottom-up)
    for (int i = cnt-1; i >= 0; i--){
      int p = order_l[i];
      int lv = 0;
      int lq = LCH[b*64 + p];
      if (lq >= 0 && isn_l[lq]) lv = lev_l[lq] + 1;
      int rq = RCH[b*64 + p];
      if (rq >= 0 && isn_l[rq] && lev_l[rq] + 1 > lv) lv = lev_l[rq] + 1;
      lev_l[p] = lv;
      int slot = atomicAdd(&LEVCNT[lv], 1);
      LEVLIST[lv*512 + slot] = (b << 8) | p;
    }
    // lps
    float lp = 0.f;
    for (int i = 0; i < cnt; i++){
      int p = order_l[i];
      int s = ns_l[p], e = ne_l[p];
      float mx = scl[s];
      for (int q = s+1; q < e; q++) mx = fmaxf(mx, scl[q]);
      float sum = 0.f;
      for (int q = s; q < e; q++) sum += expf(scl[q] - mx);
      lp += (float)(e - s) * (scl[p] - (mx + logf(sum)));
    }
    OUT[32768 + b] = lp;
    // root rep
    int rp;
    if (len <= 0) rp = 0;
    else if (len == 1) rp = 0;
    else { rp = 0; float m2 = scl[0]; for (int q = 1; q < len; q++){ if (scl[q] > m2){ m2 = scl[q]; rp = q; } } }
    ROOTP[b] = rp;
  }
}

// ---------------- k_lstm_step: [update h[t-1] from prev partials] + [recurrent partials for step t]
// grid 256: kc = blockIdx>>4 (16 k-chunks of 64), jt = blockIdx&15 (16 j-tiles of 64)
__global__ __launch_bounds__(256) void k_lstm_step(int t,
      const float* __restrict__ GX, const float* __restrict__ WT,
      float* __restrict__ HS, float* __restrict__ CS,
      const float* __restrict__ GPr, float* __restrict__ GPw){
  __shared__ float Hc[64][16];   // [kk][b]
  int kc = blockIdx.x >> 4, jt = blockIdx.x & 15;
  if (t == 0){
    for (int idx = threadIdx.x; idx < 1024; idx += 256){
      Hc[idx >> 4][idx & 15] = 0.f;
    }
  } else {
    for (int idx = threadIdx.x; idx < 1024; idx += 256){
      int b = idx >> 6, kk = idx & 63;
      int j = kc*64 + kk;
      int base = (b*64 + (t-1))*4096 + j;
      float g0 = GX[base], g1 = GX[base+1024], g2 = GX[base+2048], g3 = GX[base+3072];
      for (int c2 = 0; c2 < 16; c2++){
        const float* gp = GPr + (c2*16 + b)*4096 + j;
        g0 += gp[0]; g1 += gp[1024]; g2 += gp[2048]; g3 += gp[3072];
      }
      float cp = (t >= 2) ? CS[(b*64 + t-2)*1024 + j] : 0.f;
      float iv = sigf(g0), fv = sigf(g1), gv = tanhf(g2), ov = sigf(g3);
      float c = fv*cp + iv*gv;
      float h = ov*tanhf(c);
      Hc[kk][b] = h;
      if (jt == 0){
        HS[(b*64 + t-1)*1024 + j] = h;
        CS[(b*64 + t-1)*1024 + j] = c;
      }
    }
  }
  __syncthreads();
  int jl = threadIdx.x & 63, g = threadIdx.x >> 6;
  int j = jt*64 + jl;
  int r = g*1024 + j;
  float acc[16] = {0,0,0,0,0,0,0,0,0,0,0,0,0,0,0,0};
  const float* wp = WT + (kc*64)*4096 + r;
  #pragma unroll 8
  for (int kk = 0; kk < 64; kk++){
    float w = wp[kk*4096];
    const float4* hp = (const float4*)&Hc[kk][0];
    float4 h0 = hp[0], h1 = hp[1], h2 = hp[2], h3 = hp[3];
    acc[0]  += w*h0.x; acc[1]  += w*h0.y; acc[2]  += w*h0.z; acc[3]  += w*h0.w;
    acc[4]  += w*h1.x; acc[5]  += w*h1.y; acc[6]  += w*h1.z; acc[7]  += w*h1.w;
    acc[8]  += w*h2.x; acc[9]  += w*h2.y; acc[10] += w*h2.z; acc[11] += w*h2.w;
    acc[12] += w*h3.x; acc[13] += w*h3.y; acc[14] += w*h3.z; acc[15] += w*h3.w;
  }
  float* o = GPw + (kc*16)*4096 + r;
  #pragma unroll
  for (int b = 0; b < 16; b++) o[b*4096] = acc[b];
}

// ---------------- k_lstm_final: produce h[63], c[63]
__global__ __launch_bounds__(256) void k_lstm_final(const float* __restrict__ GX,
      const float* __restrict__ GPr, float* __restrict__ HS, float* __restrict__ CS){
  int idx = blockIdx.x*256 + threadIdx.x;   // 16384
  int b = idx >> 10, j = idx & 1023;
  int base = (b*64 + 63)*4096 + j;
  float g0 = GX[base], g1 = GX[base+1024], g2 = GX[base+2048], g3 = GX[base+3072];
  for (int c2 = 0; c2 < 16; c2++){
    const float* gp = GPr + (c2*16 + b)*4096 + j;
    g0 += gp[0]; g1 += gp[1024]; g2 += gp[2048]; g3 += gp[3072];
  }
  float cp = CS[(b*64 + 62)*1024 + j];
  float iv = sigf(g0), fv = sigf(g1), gv = tanhf(g2), ov = sigf(g3);
  float c = fv*cp + iv*gv;
  float h = ov*tanhf(c);
  HS[(b*64 + 63)*1024 + j] = h;
  CS[(b*64 + 63)*1024 + j] = c;
}

// ---------------- k_tree_gemm: level-batched gates GEMM  G[n][r] = tl_w[r]·[hl;hr;hm](n)
// tiles: 16 rows x 64 nodes, K=3072 staged in LDS
__global__ __launch_bounds__(256) void k_tree_gemm(int v,
      const float* __restrict__ tl_w, const float* __restrict__ HS,
      const int* __restrict__ LCH, const int* __restrict__ RCH,
      const int* __restrict__ LEVCNT, const int* __restrict__ LEVLIST,
      float* __restrict__ G){
  int nc = LEVCNT[v];
  if (nc == 0) return;
  int ntiles = (nc + 63) >> 6;
  int ntasks = ntiles * 384;
  __shared__ float Wt[64][17];
  __shared__ float Ht[64][68];
  __shared__ int nb[64], np[64], nql[64], nqr[64];
  for (int task = blockIdx.x; task < ntasks; task += gridDim.x){
    int rt = task % 384, nt = task / 384;
    int r0 = rt*16, n0 = nt*64;
    if (threadIdx.x < 64){
      int n = n0 + threadIdx.x;
      if (n < nc){
        int e = LEVLIST[v*512 + n];
        int bb = e >> 8, p = e & 255;
        nb[threadIdx.x] = bb; np[threadIdx.x] = p;
        nql[threadIdx.x] = LCH[bb*64 + p];
        nqr[threadIdx.x] = RCH[bb*64 + p];
      } else {
        nb[threadIdx.x] = -1; np[threadIdx.x] = -1;
        nql[threadIdx.x] = -1; nqr[threadIdx.x] = -1;
      }
    }
    __syncthreads();
    float acc[4] = {0.f, 0.f, 0.f, 0.f};
    int rl = threadIdx.x & 15, ng = threadIdx.x >> 4;
    for (int k0 = 0; k0 < 3072; k0 += 64){
      for (int idx = threadIdx.x; idx < 1024; idx += 256){
        int rr = idx >> 6, kk = idx & 63;
        Wt[kk][rr] = tl_w[(r0 + rr)*3072 + k0 + kk];
      }
      int seg = k0 >> 10;
      int ko0 = k0 & 1023;
      for (int idx = threadIdx.x; idx < 4096; idx += 256){
        int nl = idx >> 6, kk = idx & 63;
        int bb = nb[nl];
        int q = (seg == 0) ? nql[nl] : (seg == 1) ? nqr[nl] : np[nl];
        float vv = 0.f;
        if (bb >= 0 && q >= 0) vv = HS[(bb*64 + q)*1024 + ko0 + kk];
        Ht[kk][nl] = vv;
      }
      __syncthreads();
      #pragma unroll 8
      for (int kk = 0; kk < 64; kk++){
        float w = Wt[kk][rl];
        float4 h4 = *(const float4*)&Ht[kk][ng*4];
        acc[0] += w*h4.x; acc[1] += w*h4.y; acc[2] += w*h4.z; acc[3] += w*h4.w;
      }
      __syncthreads();
    }
    #pragma unroll
    for (int jj = 0; jj < 4; jj++){
      int n = n0 + ng*4 + jj;
      if (n < nc) G[n*6144 + r0 + rl] = acc[jj];
    }
    __syncthreads();
  }
}

// ---------------- k_tree_upd: per-level state update (in place into HS/CS)
__global__ __launch_bounds__(256) void k_tree_upd(int v,
      const float* __restrict__ tl_b, const float* __restrict__ G,
      const int* __restrict__ LCH, const int* __restrict__ RCH,
      const int* __restrict__ LEVCNT, const int* __restrict__ LEVLIST,
      float* __restrict__ HS, float* __restrict__ CS){
  int nc = LEVCNT[v];
  if (nc == 0) return;
  int total = nc * 1024;
  for (int idx = blockIdx.x*256 + threadIdx.x; idx < total; idx += gridDim.x*256){
    int n = idx >> 10, j = idx & 1023;
    int e = LEVLIST[v*512 + n];
    int b = e >> 8, p = e & 255;
    const float* g = G + n*6144;
    float gi  = g[j]        + tl_b[j];
    float gfl = g[1024 + j] + tl_b[1024 + j];
    float gfr = g[2048 + j] + tl_b[2048 + j];
    float gfm = g[3072 + j] + tl_b[3072 + j];
    float gu  = g[4096 + j] + tl_b[4096 + j];
    float go  = g[5120 + j] + tl_b[5120 + j];
    int lq = LCH[b*64 + p], rq = RCH[b*64 + p];
    float cl = (lq >= 0) ? CS[(b*64 + lq)*1024 + j] : 0.f;
    float cr = (rq >= 0) ? CS[(b*64 + rq)*1024 + j] : 0.f;
    float cm = CS[(b*64 + p)*1024 + j];
    float c = sigf(gfl)*cl + sigf(gfr)*cr + sigf(gfm)*cm + sigf(gi)*tanhf(gu);
    float h = sigf(go)*tanhf(c);
    HS[(b*64 + p)*1024 + j] = h;
    CS[(b*64 + p)*1024 + j] = c;
  }
}

// ---------------- k_root: gather root states to output
__global__ __launch_bounds__(256) void k_root(const int* __restrict__ ROOTP,
      const float* __restrict__ HS, const float* __restrict__ CS,
      float* __restrict__ OUT){
  int idx = blockIdx.x*256 + threadIdx.x;  // 16384
  int b = idx >> 10, j = idx & 1023;
  int rp = ROOTP[b];
  OUT[b*1024 + j]         = HS[(b*64 + rp)*1024 + j];
  OUT[16384 + b*1024 + j] = CS[(b*64 + rp)*1024 + j];
}

extern "C" void kernel_launch(void* const* d_in, const int* in_sizes, int n_in,
                              void* d_out, int out_size, void* d_ws, size_t ws_size,
                              hipStream_t stream) {
  (void)in_sizes; (void)n_in; (void)out_size; (void)ws_size;
  const float* emb    = (const float*)d_in[0];
  // d_in[1] = sentence_word (unused: rank_input='w' uses embeddings)
  const int*   length = (const int*)  d_in[2];
  const float* w_ih   = (const float*)d_in[3];
  const float* w_hh   = (const float*)d_in[4];
  const float* b_ih   = (const float*)d_in[5];
  const float* b_hh   = (const float*)d_in[6];
  const float* tl_w   = (const float*)d_in[7];
  const float* tl_b   = (const float*)d_in[8];
  const float* rk_w1  = (const float*)d_in[9];
  const float* rk_w2  = (const float*)d_in[10];
  float* OUT = (float*)d_out;

  float* ws_f = (float*)d_ws;
  float* WHHT = ws_f;                 // 4,194,304 floats (reused as tree G after LSTM)
  float* GX   = ws_f + 4194304;       // 4,194,304
  float* HS   = ws_f + 8388608;       // 1,048,576
  float* CS   = ws_f + 9437184;       // 1,048,576
  float* GP   = ws_f + 10485760;      // 2 x 1,048,576
  float* SC   = ws_f + 12582912;      // 1,024
  int*   IW   = (int*)(ws_f + 12583936);
  int* LCH     = IW;
  int* RCH     = IW + 1024;
  int* LEVCNT  = IW + 2048;
  int* LEVLIST = IW + 2112;
  int* ROOTP   = IW + 34880;
  float* G = WHHT;  // overlay: tree gate scratch (512*6144 <= 4,194,304)

  const int GPC = 16*16*4096;  // one parity chunk

  k_prep<<<4096, 256, 0, stream>>>(w_hh, WHHT, LEVCNT);
  k_rank<<<1024, 128, 0, stream>>>(emb, rk_w1, rk_w2, SC);
  k_gx<<<1024, 256, 0, stream>>>(emb, w_ih, b_ih, b_hh, GX);
  k_build<<<16, 64, 0, stream>>>(SC, length, LCH, RCH, LEVCNT, LEVLIST, ROOTP, OUT);

  for (int t = 0; t < 64; t++){
    int par = t & 1;
    k_lstm_step<<<256, 256, 0, stream>>>(t, GX, WHHT, HS, CS,
                                         GP + (1 - par)*GPC, GP + par*GPC);
  }
  k_lstm_final<<<64, 256, 0, stream>>>(GX, GP + 1*GPC, HS, CS);

  for (int v = 0; v < 63; v++){
    k_tree_gemm<<<768, 256, 0, stream>>>(v, tl_w, HS, LCH, RCH, LEVCNT, LEVLIST, G);
    k_tree_upd<<<256, 256, 0, stream>>>(v, tl_b, G, LCH, RCH, LEVCNT, LEVLIST, HS, CS);
  }
  k_root<<<64, 256, 0, stream>>>(ROOTP, HS, CS, OUT);
}

// Round 2
// 2868.785 us; speedup vs baseline: 1.7991x; 1.7991x over previous
//
#include <hip/hip_runtime.h>

#define NB 16
#define NL 64

typedef __attribute__((ext_vector_type(8))) short bf16x8;
typedef __attribute__((ext_vector_type(4))) float f32x4;

__device__ __forceinline__ float sigf(float x){ return 1.0f/(1.0f + expf(-x)); }

__device__ __forceinline__ short f2bf(float x){
  union { float f; unsigned u; } v; v.f = x;
  unsigned r = v.u + 0x7fffu + ((v.u >> 16) & 1u);
  return (short)(r >> 16);
}

// ---------------- k_prep: transpose w_hh (4096x1024) -> whhT[k][r] (1024x4096); zero levcnt
__global__ __launch_bounds__(256) void k_prep(const float* __restrict__ w_hh,
                                              float* __restrict__ whhT,
                                              int* __restrict__ levcnt){
  __shared__ float tl[32][33];
  int tr = blockIdx.x & 127;   // r tile [0,128)
  int tk = blockIdx.x >> 7;    // k tile [0,32)
  for (int idx = threadIdx.x; idx < 1024; idx += 256){
    int lr = idx >> 5, lk = idx & 31;
    tl[lr][lk] = w_hh[(tr*32 + lr)*1024 + tk*32 + lk];
  }
  __syncthreads();
  for (int idx = threadIdx.x; idx < 1024; idx += 256){
    int lk = idx >> 5, lr = idx & 31;
    whhT[(tk*32 + lk)*4096 + tr*32 + lr] = tl[lr][lk];
  }
  if (blockIdx.x == 0 && threadIdx.x < 64) levcnt[threadIdx.x] = 0;
}

// ---------------- k_rank: sc[bl] = relu(emb[bl]·w1[j]) · w2[j] summed over j
__global__ __launch_bounds__(128) void k_rank(const float* __restrict__ emb,
                                              const float* __restrict__ w1,
                                              const float* __restrict__ w2,
                                              float* __restrict__ SC){
  int bl = blockIdx.x;
  int j  = threadIdx.x;
  const float* e = emb + bl*1024;
  const float* w = w1 + j*1024;
  float acc = 0.f;
  for (int k = 0; k < 1024; k += 4){
    float4 ev = *(const float4*)(e + k);
    float4 wv = *(const float4*)(w + k);
    acc += ev.x*wv.x + ev.y*wv.y + ev.z*wv.z + ev.w*wv.w;
  }
  float s = fmaxf(acc, 0.f) * w2[j];
  __shared__ float red[128];
  red[j] = s;
  __syncthreads();
  for (int st = 64; st > 0; st >>= 1){
    if (j < st) red[j] += red[j + st];
    __syncthreads();
  }
  if (j == 0) SC[bl] = red[0];
}

// ---------------- k_gx (MFMA bf16): GX[bl][r] = emb[bl]·w_ih[r] + b_ih[r] + b_hh[r]
// A = w_ih (M=4096 rows), B = emb (N=1024 rows), K=1024. Tile 64x64, 4 waves.
__global__ __launch_bounds__(256) void k_gx(const float* __restrict__ emb,
                                            const float* __restrict__ w_ih,
                                            const float* __restrict__ b_ih,
                                            const float* __restrict__ b_hh,
                                            float* __restrict__ GX){
  __shared__ short Ws[64][72];
  __shared__ short Es[64][72];
  int mt = blockIdx.x >> 4;   // 0..63  (w_ih row tiles)
  int nt4 = blockIdx.x & 15;  // 0..15  (emb row tiles)
  int r0 = mt*64, n0 = nt4*64;
  int lane = threadIdx.x & 63, w = threadIdx.x >> 6;
  int m16 = lane & 15, quad = lane >> 4;
  int srr = threadIdx.x >> 2, skk = (threadIdx.x & 3)*16;
  f32x4 acc[4] = {{0,0,0,0},{0,0,0,0},{0,0,0,0},{0,0,0,0}};
  for (int k0 = 0; k0 < 1024; k0 += 64){
    #pragma unroll
    for (int i = 0; i < 4; i++){
      float4 v = *(const float4*)(w_ih + (r0 + srr)*1024 + k0 + skk + i*4);
      Ws[srr][skk + i*4 + 0] = f2bf(v.x); Ws[srr][skk + i*4 + 1] = f2bf(v.y);
      Ws[srr][skk + i*4 + 2] = f2bf(v.z); Ws[srr][skk + i*4 + 3] = f2bf(v.w);
      float4 u = *(const float4*)(emb + (n0 + srr)*1024 + k0 + skk + i*4);
      Es[srr][skk + i*4 + 0] = f2bf(u.x); Es[srr][skk + i*4 + 1] = f2bf(u.y);
      Es[srr][skk + i*4 + 2] = f2bf(u.z); Es[srr][skk + i*4 + 3] = f2bf(u.w);
    }
    __syncthreads();
    #pragma unroll
    for (int ks = 0; ks < 64; ks += 32){
      bf16x8 a = *(bf16x8*)&Ws[w*16 + m16][ks + quad*8];
      #pragma unroll
      for (int nt = 0; nt < 4; nt++){
        bf16x8 b = *(bf16x8*)&Es[nt*16 + m16][ks + quad*8];
        acc[nt] = __builtin_amdgcn_mfma_f32_16x16x32_bf16(a, b, acc[nt], 0, 0, 0);
      }
    }
    __syncthreads();
  }
  int rbase = r0 + w*16 + quad*4;
  f32x4 bi = *(const f32x4*)(b_ih + rbase);
  f32x4 bh = *(const f32x4*)(b_hh + rbase);
  #pragma unroll
  for (int nt = 0; nt < 4; nt++){
    int n = n0 + nt*16 + m16;      // emb row (bl)
    f32x4 o = acc[nt] + bi + bh;
    *(f32x4*)(GX + n*4096 + rbase) = o;
  }
}

// ---------------- k_build: per-sentence greedy tree, levels, level lists, lps
__global__ __launch_bounds__(64) void k_build(const float* __restrict__ SC,
                                              const int* __restrict__ length,
                                              int* __restrict__ LCH, int* __restrict__ RCH,
                                              int* __restrict__ LEVCNT, int* __restrict__ LEVLIST,
                                              int* __restrict__ ROOTP,
                                              float* __restrict__ OUT){
  __shared__ float scl[64];
  __shared__ int stk_s[64], stk_e[64], order_l[64];
  __shared__ int isn_l[64], lev_l[64], ns_l[64], ne_l[64];
  int b = blockIdx.x;
  if (threadIdx.x < 64){
    scl[threadIdx.x] = SC[b*64 + threadIdx.x];
    isn_l[threadIdx.x] = 0;
  }
  __syncthreads();
  if (threadIdx.x == 0){
    int len = length[b];
    int cnt = 0, sp = 0;
    if (len >= 2){ stk_s[0] = 0; stk_e[0] = len; sp = 1; }
    while (sp > 0){
      sp--;
      int s = stk_s[sp], e = stk_e[sp];
      int pos = s; float mx = scl[s];
      for (int q = s+1; q < e; q++){ if (scl[q] > mx){ mx = scl[q]; pos = q; } }
      order_l[cnt++] = pos;
      int lq;
      if (pos - s <= 0) lq = -1;
      else if (pos - s == 1) lq = s;
      else { lq = s; float m2 = scl[s]; for (int q = s+1; q < pos; q++){ if (scl[q] > m2){ m2 = scl[q]; lq = q; } } }
      int rq;
      if (e - (pos+1) <= 0) rq = -1;
      else if (e - (pos+1) == 1) rq = pos+1;
      else { rq = pos+1; float m2 = scl[pos+1]; for (int q = pos+2; q < e; q++){ if (scl[q] > m2){ m2 = scl[q]; rq = q; } } }
      LCH[b*64 + pos] = lq; RCH[b*64 + pos] = rq;
      ns_l[pos] = s; ne_l[pos] = e; isn_l[pos] = 1;
      if (pos - s >= 2){ stk_s[sp] = s; stk_e[sp] = pos; sp++; }
      if (e - pos - 1 >= 2){ stk_s[sp] = pos+1; stk_e[sp] = e; sp++; }
    }
    for (int i = cnt-1; i >= 0; i--){
      int p = order_l[i];
      int lv = 0;
      int lq = LCH[b*64 + p];
      if (lq >= 0 && isn_l[lq]) lv = lev_l[lq] + 1;
      int rq = RCH[b*64 + p];
      if (rq >= 0 && isn_l[rq] && lev_l[rq] + 1 > lv) lv = lev_l[rq] + 1;
      lev_l[p] = lv;
      int slot = atomicAdd(&LEVCNT[lv], 1);
      LEVLIST[lv*512 + slot] = (b << 8) | p;
    }
    float lp = 0.f;
    for (int i = 0; i < cnt; i++){
      int p = order_l[i];
      int s = ns_l[p], e = ne_l[p];
      float mx = scl[s];
      for (int q = s+1; q < e; q++) mx = fmaxf(mx, scl[q]);
      float sum = 0.f;
      for (int q = s; q < e; q++) sum += expf(scl[q] - mx);
      lp += (float)(e - s) * (scl[p] - (mx + logf(sum)));
    }
    OUT[32768 + b] = lp;
    int rp;
    if (len <= 1) rp = 0;
    else { rp = 0; float m2 = scl[0]; for (int q = 1; q < len; q++){ if (scl[q] > m2){ m2 = scl[q]; rp = q; } } }
    ROOTP[b] = rp;
  }
}

// ---------------- k_lstm_step
__global__ __launch_bounds__(256) void k_lstm_step(int t,
      const float* __restrict__ GX, const float* __restrict__ WT,
      float* __restrict__ HS, float* __restrict__ CS,
      const float* __restrict__ GPr, float* __restrict__ GPw){
  __shared__ float Hc[64][16];   // [kk][b]
  int kc = blockIdx.x >> 4, jt = blockIdx.x & 15;
  if (t == 0){
    for (int idx = threadIdx.x; idx < 1024; idx += 256){
      Hc[idx >> 4][idx & 15] = 0.f;
    }
  } else {
    for (int idx = threadIdx.x; idx < 1024; idx += 256){
      int b = idx >> 6, kk = idx & 63;
      int j = kc*64 + kk;
      int base = (b*64 + (t-1))*4096 + j;
      float g0 = GX[base], g1 = GX[base+1024], g2 = GX[base+2048], g3 = GX[base+3072];
      for (int c2 = 0; c2 < 16; c2++){
        const float* gp = GPr + (c2*16 + b)*4096 + j;
        g0 += gp[0]; g1 += gp[1024]; g2 += gp[2048]; g3 += gp[3072];
      }
      float cp = (t >= 2) ? CS[(b*64 + t-2)*1024 + j] : 0.f;
      float iv = sigf(g0), fv = sigf(g1), gv = tanhf(g2), ov = sigf(g3);
      float c = fv*cp + iv*gv;
      float h = ov*tanhf(c);
      Hc[kk][b] = h;
      if (jt == 0){
        HS[(b*64 + t-1)*1024 + j] = h;
        CS[(b*64 + t-1)*1024 + j] = c;
      }
    }
  }
  __syncthreads();
  int jl = threadIdx.x & 63, g = threadIdx.x >> 6;
  int j = jt*64 + jl;
  int r = g*1024 + j;
  float acc[16] = {0,0,0,0,0,0,0,0,0,0,0,0,0,0,0,0};
  const float* wp = WT + (kc*64)*4096 + r;
  #pragma unroll 8
  for (int kk = 0; kk < 64; kk++){
    float w = wp[kk*4096];
    const float4* hp = (const float4*)&Hc[kk][0];
    float4 h0 = hp[0], h1 = hp[1], h2 = hp[2], h3 = hp[3];
    acc[0]  += w*h0.x; acc[1]  += w*h0.y; acc[2]  += w*h0.z; acc[3]  += w*h0.w;
    acc[4]  += w*h1.x; acc[5]  += w*h1.y; acc[6]  += w*h1.z; acc[7]  += w*h1.w;
    acc[8]  += w*h2.x; acc[9]  += w*h2.y; acc[10] += w*h2.z; acc[11] += w*h2.w;
    acc[12] += w*h3.x; acc[13] += w*h3.y; acc[14] += w*h3.z; acc[15] += w*h3.w;
  }
  float* o = GPw + (kc*16)*4096 + r;
  #pragma unroll
  for (int b = 0; b < 16; b++) o[b*4096] = acc[b];
}

// ---------------- k_lstm_final
__global__ __launch_bounds__(256) void k_lstm_final(const float* __restrict__ GX,
      const float* __restrict__ GPr, float* __restrict__ HS, float* __restrict__ CS){
  int idx = blockIdx.x*256 + threadIdx.x;   // 16384
  int b = idx >> 10, j = idx & 1023;
  int base = (b*64 + 63)*4096 + j;
  float g0 = GX[base], g1 = GX[base+1024], g2 = GX[base+2048], g3 = GX[base+3072];
  for (int c2 = 0; c2 < 16; c2++){
    const float* gp = GPr + (c2*16 + b)*4096 + j;
    g0 += gp[0]; g1 += gp[1024]; g2 += gp[2048]; g3 += gp[3072];
  }
  float cp = CS[(b*64 + 62)*1024 + j];
  float iv = sigf(g0), fv = sigf(g1), gv = tanhf(g2), ov = sigf(g3);
  float c = fv*cp + iv*gv;
  float h = ov*tanhf(c);
  HS[(b*64 + 63)*1024 + j] = h;
  CS[(b*64 + 63)*1024 + j] = c;
}

// ---------------- k_tree_gather: Hcat[n][3072] bf16 = [h(l); h(r); h(m)] for level-v node n
__global__ __launch_bounds__(256) void k_tree_gather(int v,
      const float* __restrict__ HS,
      const int* __restrict__ LCH, const int* __restrict__ RCH,
      const int* __restrict__ LEVCNT, const int* __restrict__ LEVLIST,
      short* __restrict__ HCAT){
  int nc = LEVCNT[v];
  int ncpad = (nc + 63) & ~63;
  int n = blockIdx.x;
  if (n >= ncpad) return;
  int t = threadIdx.x;
  if (n >= nc){
    short4 z = {0,0,0,0};
    #pragma unroll
    for (int seg = 0; seg < 3; seg++)
      *(short4*)(HCAT + n*3072 + seg*1024 + t*4) = z;
    return;
  }
  int e = LEVLIST[v*512 + n];
  int b = e >> 8, p = e & 255;
  int q0 = LCH[b*64 + p], q1 = RCH[b*64 + p], q2 = p;
  int qs[3] = {q0, q1, q2};
  #pragma unroll
  for (int seg = 0; seg < 3; seg++){
    int q = qs[seg];
    short4 o;
    if (q >= 0){
      float4 vv = *(const float4*)(HS + (b*64 + q)*1024 + t*4);
      o.x = f2bf(vv.x); o.y = f2bf(vv.y); o.z = f2bf(vv.z); o.w = f2bf(vv.w);
    } else {
      o.x = o.y = o.z = o.w = 0;
    }
    *(short4*)(HCAT + n*3072 + seg*1024 + t*4) = o;
  }
}

// ---------------- k_tree_mm (MFMA bf16): G[n][r] = tl_w[r]·Hcat[n],  M=6144, N=nc, K=3072
__global__ __launch_bounds__(256) void k_tree_mm(int v,
      const float* __restrict__ tl_w, const short* __restrict__ HCAT,
      const int* __restrict__ LEVCNT,
      float* __restrict__ G){
  int nc = LEVCNT[v];
  int ntile = blockIdx.x & 7;
  int n0 = ntile*64;
  if (n0 >= nc) return;
  int mt = blockIdx.x >> 3;     // 0..95
  int r0 = mt*64;
  __shared__ short Ws[64][72];
  __shared__ short Hs[64][72];
  int lane = threadIdx.x & 63, w = threadIdx.x >> 6;
  int m16 = lane & 15, quad = lane >> 4;
  int srr = threadIdx.x >> 2, skk = (threadIdx.x & 3)*16;
  f32x4 acc[4] = {{0,0,0,0},{0,0,0,0},{0,0,0,0},{0,0,0,0}};
  for (int k0 = 0; k0 < 3072; k0 += 64){
    #pragma unroll
    for (int i = 0; i < 4; i++){
      float4 vv = *(const float4*)(tl_w + (r0 + srr)*3072 + k0 + skk + i*4);
      Ws[srr][skk + i*4 + 0] = f2bf(vv.x); Ws[srr][skk + i*4 + 1] = f2bf(vv.y);
      Ws[srr][skk + i*4 + 2] = f2bf(vv.z); Ws[srr][skk + i*4 + 3] = f2bf(vv.w);
    }
    *(bf16x8*)&Hs[srr][skk]     = *(const bf16x8*)(HCAT + (n0 + srr)*3072 + k0 + skk);
    *(bf16x8*)&Hs[srr][skk + 8] = *(const bf16x8*)(HCAT + (n0 + srr)*3072 + k0 + skk + 8);
    __syncthreads();
    #pragma unroll
    for (int ks = 0; ks < 64; ks += 32){
      bf16x8 a = *(bf16x8*)&Ws[w*16 + m16][ks + quad*8];
      #pragma unroll
      for (int nt = 0; nt < 4; nt++){
        bf16x8 b = *(bf16x8*)&Hs[nt*16 + m16][ks + quad*8];
        acc[nt] = __builtin_amdgcn_mfma_f32_16x16x32_bf16(a, b, acc[nt], 0, 0, 0);
      }
    }
    __syncthreads();
  }
  int rbase = r0 + w*16 + quad*4;
  #pragma unroll
  for (int nt = 0; nt < 4; nt++){
    int n = n0 + nt*16 + m16;
    if (n < nc) *(f32x4*)(G + n*6144 + rbase) = acc[nt];
  }
}

// ---------------- k_tree_upd: per-level state update (in place into HS/CS)
__global__ __launch_bounds__(256) void k_tree_upd(int v,
      const float* __restrict__ tl_b, const float* __restrict__ G,
      const int* __restrict__ LCH, const int* __restrict__ RCH,
      const int* __restrict__ LEVCNT, const int* __restrict__ LEVLIST,
      float* __restrict__ HS, float* __restrict__ CS){
  int nc = LEVCNT[v];
  if (nc == 0) return;
  int total = nc * 1024;
  for (int idx = blockIdx.x*256 + threadIdx.x; idx < total; idx += gridDim.x*256){
    int n = idx >> 10, j = idx & 1023;
    int e = LEVLIST[v*512 + n];
    int b = e >> 8, p = e & 255;
    const float* g = G + n*6144;
    float gi  = g[j]        + tl_b[j];
    float gfl = g[1024 + j] + tl_b[1024 + j];
    float gfr = g[2048 + j] + tl_b[2048 + j];
    float gfm = g[3072 + j] + tl_b[3072 + j];
    float gu  = g[4096 + j] + tl_b[4096 + j];
    float go  = g[5120 + j] + tl_b[5120 + j];
    int lq = LCH[b*64 + p], rq = RCH[b*64 + p];
    float cl = (lq >= 0) ? CS[(b*64 + lq)*1024 + j] : 0.f;
    float cr = (rq >= 0) ? CS[(b*64 + rq)*1024 + j] : 0.f;
    float cm = CS[(b*64 + p)*1024 + j];
    float c = sigf(gfl)*cl + sigf(gfr)*cr + sigf(gfm)*cm + sigf(gi)*tanhf(gu);
    float h = sigf(go)*tanhf(c);
    HS[(b*64 + p)*1024 + j] = h;
    CS[(b*64 + p)*1024 + j] = c;
  }
}

// ---------------- k_root: gather root states to output
__global__ __launch_bounds__(256) void k_root(const int* __restrict__ ROOTP,
      const float* __restrict__ HS, const float* __restrict__ CS,
      float* __restrict__ OUT){
  int idx = blockIdx.x*256 + threadIdx.x;  // 16384
  int b = idx >> 10, j = idx & 1023;
  int rp = ROOTP[b];
  OUT[b*1024 + j]         = HS[(b*64 + rp)*1024 + j];
  OUT[16384 + b*1024 + j] = CS[(b*64 + rp)*1024 + j];
}

extern "C" void kernel_launch(void* const* d_in, const int* in_sizes, int n_in,
                              void* d_out, int out_size, void* d_ws, size_t ws_size,
                              hipStream_t stream) {
  (void)in_sizes; (void)n_in; (void)out_size; (void)ws_size;
  const float* emb    = (const float*)d_in[0];
  const int*   length = (const int*)  d_in[2];
  const float* w_ih   = (const float*)d_in[3];
  const float* w_hh   = (const float*)d_in[4];
  const float* b_ih   = (const float*)d_in[5];
  const float* b_hh   = (const float*)d_in[6];
  const float* tl_w   = (const float*)d_in[7];
  const float* tl_b   = (const float*)d_in[8];
  const float* rk_w1  = (const float*)d_in[9];
  const float* rk_w2  = (const float*)d_in[10];
  float* OUT = (float*)d_out;

  float* ws_f = (float*)d_ws;
  float* WHHT = ws_f;                 // 4,194,304 f (reused as tree G after LSTM)
  float* GX   = ws_f + 4194304;       // 4,194,304 f (reused as HCAT bf16 after LSTM)
  float* HS   = ws_f + 8388608;       // 1,048,576 f
  float* CS   = ws_f + 9437184;       // 1,048,576 f
  float* GP   = ws_f + 10485760;      // 2 x 1,048,576 f
  float* SC   = ws_f + 12582912;      // 1,024 f
  int*   IW   = (int*)(ws_f + 12583936);
  int* LCH     = IW;
  int* RCH     = IW + 1024;
  int* LEVCNT  = IW + 2048;
  int* LEVLIST = IW + 2112;
  int* ROOTP   = IW + 34880;
  float* G = WHHT;            // overlay: 512*6144 f32 <= 4,194,304
  short* HCAT = (short*)GX;   // overlay: 512*3072 bf16 <= region

  const int GPC = 16*16*4096;

  k_prep<<<4096, 256, 0, stream>>>(w_hh, WHHT, LEVCNT);
  k_rank<<<1024, 128, 0, stream>>>(emb, rk_w1, rk_w2, SC);
  k_gx<<<1024, 256, 0, stream>>>(emb, w_ih, b_ih, b_hh, GX);
  k_build<<<16, 64, 0, stream>>>(SC, length, LCH, RCH, LEVCNT, LEVLIST, ROOTP, OUT);

  for (int t = 0; t < 64; t++){
    int par = t & 1;
    k_lstm_step<<<256, 256, 0, stream>>>(t, GX, WHHT, HS, CS,
                                         GP + (1 - par)*GPC, GP + par*GPC);
  }
  k_lstm_final<<<64, 256, 0, stream>>>(GX, GP + 1*GPC, HS, CS);

  for (int v = 0; v < 63; v++){
    k_tree_gather<<<512, 256, 0, stream>>>(v, HS, LCH, RCH, LEVCNT, LEVLIST, HCAT);
    k_tree_mm<<<768, 256, 0, stream>>>(v, tl_w, HCAT, LEVCNT, G);
    k_tree_upd<<<256, 256, 0, stream>>>(v, tl_b, G, LCH, RCH, LEVCNT, LEVLIST, HS, CS);
  }
  k_root<<<64, 256, 0, stream>>>(ROOTP, HS, CS, OUT);
}